// Round 12
// baseline (73.622 us; speedup 1.0000x reference)
//
#include <hip/hip_runtime.h>

#define D_FEAT 96
#define P_DIM 96
#define OUT_DIM 192
#define SCAN_BLK 256
#define NODES_PER_BLK 8
#define LPN 24          // f32 path: lanes per node (24 x float4)
#define RNG_SHIFT 8     // 256 nodes per range
#define RNG_NODES 256
#define NBLK_A 256      // binning blocks (== SCAN_BLK so scan chunks == ranges)
#define BIG_T 1024      // threads for binning kernels
#define FS_CAP 6144     // finesort LDS window capacity (ints, 24KB)

// Target is guaranteed gfx950 (has fp8-conversion-insts). __has_builtin is
// FALSE in the HIP host pass, which silently disabled the fp8 tier in R11 --
// the builtins are device-only and fine inside __global__ bodies.
#define HAVE_FP8 1

typedef float f32x4 __attribute__((ext_vector_type(4)));
typedef float f32x2 __attribute__((ext_vector_type(2)));
typedef unsigned int u32;
typedef u32 u32x4 __attribute__((ext_vector_type(4)));

// ---------------- fallback (round-1) kernels ------------------------------
__global__ __launch_bounds__(256) void zero_k(float* __restrict__ out,
                                              float* __restrict__ deg,
                                              int n_out, int n_deg) {
    int stride = gridDim.x * blockDim.x;
    for (int i = blockIdx.x * blockDim.x + threadIdx.x; i < n_out; i += stride)
        out[i] = 0.0f;
    for (int i = blockIdx.x * blockDim.x + threadIdx.x; i < n_deg; i += stride)
        deg[i] = 0.0f;
}

__global__ __launch_bounds__(256) void degf_k(const int* __restrict__ dst,
                                              float* __restrict__ deg,
                                              int n_edges) {
    int e = blockIdx.x * blockDim.x + threadIdx.x;
    if (e < n_edges) atomicAdd(deg + dst[e], 1.0f);
}

__global__ __launch_bounds__(256) void scatter_k(const float* __restrict__ emb,
                                                 const int* __restrict__ src,
                                                 const int* __restrict__ dst,
                                                 float* __restrict__ out,
                                                 int n_edges) {
    int idx = blockIdx.x * blockDim.x + threadIdx.x;
    int e = idx / D_FEAT;
    if (e >= n_edges) return;
    int c = idx - e * D_FEAT;
    atomicAdd(out + (size_t)dst[e] * OUT_DIM + c, emb[(size_t)src[e] * D_FEAT + c]);
}

__global__ __launch_bounds__(256) void prompt_k(const float* __restrict__ w,
                                                const float* __restrict__ deg,
                                                float* __restrict__ out,
                                                int n_nodes) {
    int idx = blockIdx.x * blockDim.x + threadIdx.x;
    if (idx >= n_nodes * P_DIM) return;
    int v = idx / P_DIM;
    int c = idx - v * P_DIM;
    out[(size_t)v * OUT_DIM + P_DIM + c] = deg[v] * w[c];
}

// ---------------- convert helpers -------------------------------------------

__device__ __forceinline__ u32 f2bf_rn(float f) {
    u32 b = __float_as_uint(f);
    return (b + 0x7fffu + ((b >> 16) & 1u)) >> 16;   // round-to-nearest-even
}

#if HAVE_FP8
__device__ __forceinline__ u32 enc4_fp8(float a, float b, float c, float d) {
    u32 r = __builtin_amdgcn_cvt_pk_fp8_f32(a, b, 0u, false);   // bytes 0,1
    r = __builtin_amdgcn_cvt_pk_fp8_f32(c, d, r, true);          // bytes 2,3
    return r;
}
#endif

// ---------------- deterministic two-pass binned counting sort --------------

// Fused: table convert (mode 0=none, 1=bf16, 2=fp8) + per-block range hist.
// 256 blocks x 1024 threads; chunk = contiguous edge slice per block.
__global__ __launch_bounds__(BIG_T) void conv_hist_k(
        const f32x4* __restrict__ emb4, u32x4* __restrict__ embq,
        int nq, int mode,
        const int* __restrict__ dst, int* __restrict__ cnt,
        int n_edges, int nr, int chunk) {
    int b = blockIdx.x, t = threadIdx.x;
    int gs = gridDim.x * BIG_T;
    int gid = b * BIG_T + t;
    if (mode == 1) {                       // bf16: out u32x4 <- 8 f32 (2 f32x4)
        for (int i = gid; i < nq; i += gs) {
            f32x4 a = emb4[2 * i];
            f32x4 c = emb4[2 * i + 1];
            u32x4 o;
            o.x = f2bf_rn(a.x) | (f2bf_rn(a.y) << 16);
            o.y = f2bf_rn(a.z) | (f2bf_rn(a.w) << 16);
            o.z = f2bf_rn(c.x) | (f2bf_rn(c.y) << 16);
            o.w = f2bf_rn(c.z) | (f2bf_rn(c.w) << 16);
            embq[i] = o;
        }
    }
#if HAVE_FP8
    else if (mode == 2) {                  // fp8: out u32x4 <- 16 f32 (4 f32x4)
        for (int i = gid; i < nq; i += gs) {
            f32x4 a = emb4[4 * i];
            f32x4 b4 = emb4[4 * i + 1];
            f32x4 c = emb4[4 * i + 2];
            f32x4 d = emb4[4 * i + 3];
            u32x4 o;
            o.x = enc4_fp8(a.x, a.y, a.z, a.w);
            o.y = enc4_fp8(b4.x, b4.y, b4.z, b4.w);
            o.z = enc4_fp8(c.x, c.y, c.z, c.w);
            o.w = enc4_fp8(d.x, d.y, d.z, d.w);
            embq[i] = o;
        }
    }
#endif
    __shared__ int h[RNG_NODES];
    if (t < RNG_NODES) h[t] = 0;
    __syncthreads();
    int beg = b * chunk;
    int end = beg + chunk; if (end > n_edges) end = n_edges;
    for (int i = beg + t; i < end; i += BIG_T)
        atomicAdd(&h[dst[i] >> RNG_SHIFT], 1);
    __syncthreads();
    if (t < nr) cnt[t * NBLK_A + b] = h[t];
}

// Per-256-chunk exclusive scan in place; aux[r] = range total (chunk==range).
__global__ __launch_bounds__(SCAN_BLK) void scan_block_k(int* __restrict__ cnt,
                                                         int* __restrict__ aux, int n) {
    __shared__ int buf[SCAN_BLK];
    int t = threadIdx.x;
    int i = blockIdx.x * SCAN_BLK + t;
    int v = (i < n) ? cnt[i] : 0;
    buf[t] = v;
    __syncthreads();
    for (int off = 1; off < SCAN_BLK; off <<= 1) {
        int x = (t >= off) ? buf[t - off] : 0;
        __syncthreads();
        buf[t] += x;
        __syncthreads();
    }
    if (i < n) cnt[i] = buf[t] - v;
    if (t == SCAN_BLK - 1) aux[blockIdx.x] = buf[t];
}

// 256 blocks x 1024 threads: append packed (src<<8 | dst&255) into this
// block's private slice of each range region (16 edges/slice -> full lines).
__global__ __launch_bounds__(BIG_T) void binwrite_k(const int* __restrict__ src,
                                                    const int* __restrict__ dst,
                                                    const int* __restrict__ cnt,
                                                    const int* __restrict__ aux,
                                                    int* __restrict__ pack,
                                                    int n_edges, int nr, int chunk) {
    __shared__ int buf[SCAN_BLK];
    __shared__ int cur[RNG_NODES];
    int b = blockIdx.x, t = threadIdx.x;
    int av = 0;
    if (t < SCAN_BLK) { av = (t < nr) ? aux[t] : 0; buf[t] = av; }
    __syncthreads();
    for (int off = 1; off < SCAN_BLK; off <<= 1) {
        int x = 0;
        if (t < SCAN_BLK && t >= off) x = buf[t - off];
        __syncthreads();
        if (t < SCAN_BLK) buf[t] += x;
        __syncthreads();
    }
    if (t < nr) cur[t] = (buf[t] - av) + cnt[t * NBLK_A + b];
    __syncthreads();
    int beg = b * chunk;
    int end = beg + chunk; if (end > n_edges) end = n_edges;
    for (int i = beg + t; i < end; i += BIG_T) {
        int d = dst[i];
        int pos = atomicAdd(&cur[d >> RNG_SHIFT], 1);
        pack[pos] = (src[i] << RNG_SHIFT) | (d & (RNG_NODES - 1));
    }
}

// nr blocks x 1024 threads: stage window in LDS, hist + scan -> offs[], place.
__global__ __launch_bounds__(BIG_T) void finesort_k(const int* __restrict__ aux,
                                                    const int* __restrict__ pack,
                                                    int* __restrict__ offs,
                                                    int* __restrict__ sorted_src,
                                                    int n_nodes, int n_edges, int nr) {
    __shared__ int buf[SCAN_BLK];
    __shared__ int h[RNG_NODES];
    __shared__ int cur[RNG_NODES];
    __shared__ int win[FS_CAP];
    int r = blockIdx.x, t = threadIdx.x;
    int av = 0;
    if (t < SCAN_BLK) { av = (t < nr) ? aux[t] : 0; buf[t] = av; }
    __syncthreads();
    for (int off = 1; off < SCAN_BLK; off <<= 1) {
        int x = 0;
        if (t < SCAN_BLK && t >= off) x = buf[t - off];
        __syncthreads();
        if (t < SCAN_BLK) buf[t] += x;
        __syncthreads();
    }
    int start = buf[r] - aux[r];
    int end = buf[r];
    int wlen = end - start;
    bool fits = (wlen <= FS_CAP);
    if (t < RNG_NODES) h[t] = 0;
    __syncthreads();
    if (fits) {
        for (int i = t; i < wlen; i += BIG_T) {
            int p = pack[start + i];
            win[i] = p;
            atomicAdd(&h[p & (RNG_NODES - 1)], 1);
        }
    } else {
        for (int i = start + t; i < end; i += BIG_T)
            atomicAdd(&h[pack[i] & (RNG_NODES - 1)], 1);
    }
    __syncthreads();
    int v = (t < RNG_NODES) ? h[t] : 0;
    for (int off = 1; off < RNG_NODES; off <<= 1) {
        int x = 0;
        if (t < RNG_NODES && t >= off) x = h[t - off];
        __syncthreads();
        if (t < RNG_NODES) h[t] += x;
        __syncthreads();
    }
    if (t < RNG_NODES) {
        int o = start + h[t] - v;
        int node = (r << RNG_SHIFT) + t;
        if (node < n_nodes) offs[node] = o;
        cur[t] = o;
    }
    __syncthreads();
    if (fits) {
        for (int i = t; i < wlen; i += BIG_T) {
            int p = win[i];
            int pos = atomicAdd(&cur[p & (RNG_NODES - 1)], 1);
            sorted_src[pos] = p >> RNG_SHIFT;
        }
    } else {
        for (int i = start + t; i < end; i += BIG_T) {
            int p = pack[i];
            int pos = atomicAdd(&cur[p & (RNG_NODES - 1)], 1);
            sorted_src[pos] = p >> RNG_SHIFT;
        }
    }
}

// ---------------- fp8 aggregation -------------------------------------------

#if HAVE_FP8
// one node per 6 lanes; u32x4 (16 fp8) gathers; 4-deep pipelined idx loads;
// f32 accumulation; f32 output. Row = 96B = 1.5 cache lines.
#define DEC16(A, g)                                                         \
    {                                                                       \
        A[0] += __builtin_amdgcn_cvt_pk_f32_fp8((g).x, false);              \
        A[1] += __builtin_amdgcn_cvt_pk_f32_fp8((g).x, true);               \
        A[2] += __builtin_amdgcn_cvt_pk_f32_fp8((g).y, false);              \
        A[3] += __builtin_amdgcn_cvt_pk_f32_fp8((g).y, true);               \
        A[4] += __builtin_amdgcn_cvt_pk_f32_fp8((g).z, false);              \
        A[5] += __builtin_amdgcn_cvt_pk_f32_fp8((g).z, true);               \
        A[6] += __builtin_amdgcn_cvt_pk_f32_fp8((g).w, false);              \
        A[7] += __builtin_amdgcn_cvt_pk_f32_fp8((g).w, true);               \
    }

__global__ __launch_bounds__(192) void aggf8_k(
        const u32x4* __restrict__ emb8,      // [N, 6] u32x4 (fp8)
        const float* __restrict__ w,         // [96] f32
        const int* __restrict__ offs,
        const int* __restrict__ sorted_src,
        float* __restrict__ out, int n_nodes, int n_edges) {
    int t = threadIdx.x;
    int sub = t / 6;
    int lane = t - sub * 6;                  // u32x4 column 0..5 (16 feats each)
    int node = blockIdx.x * 32 + sub;
    if (node >= n_nodes) return;

    int start = offs[node];
    int endp = (node + 1 < n_nodes) ? offs[node + 1] : n_edges;
    int cnt = endp - start;
    const int* sp = sorted_src + start;

    f32x2 A[8];
    #pragma unroll
    for (int k = 0; k < 8; ++k) A[k] = (f32x2){0.f, 0.f};

    int j = 0;
    if (cnt >= 8) {
        int s0 = sp[0], s1 = sp[1], s2 = sp[2], s3 = sp[3];
        for (; j + 7 < cnt; j += 4) {
            int t0 = sp[j + 4], t1 = sp[j + 5], t2 = sp[j + 6], t3 = sp[j + 7];
            u32x4 g0 = emb8[(size_t)s0 * 6 + lane];
            u32x4 g1 = emb8[(size_t)s1 * 6 + lane];
            u32x4 g2 = emb8[(size_t)s2 * 6 + lane];
            u32x4 g3 = emb8[(size_t)s3 * 6 + lane];
            DEC16(A, g0); DEC16(A, g1); DEC16(A, g2); DEC16(A, g3);
            s0 = t0; s1 = t1; s2 = t2; s3 = t3;
        }
        u32x4 g0 = emb8[(size_t)s0 * 6 + lane];
        u32x4 g1 = emb8[(size_t)s1 * 6 + lane];
        u32x4 g2 = emb8[(size_t)s2 * 6 + lane];
        u32x4 g3 = emb8[(size_t)s3 * 6 + lane];
        DEC16(A, g0); DEC16(A, g1); DEC16(A, g2); DEC16(A, g3);
        j += 4;
    }
    for (; j + 3 < cnt; j += 4) {
        int s0 = sp[j], s1 = sp[j + 1], s2 = sp[j + 2], s3 = sp[j + 3];
        u32x4 g0 = emb8[(size_t)s0 * 6 + lane];
        u32x4 g1 = emb8[(size_t)s1 * 6 + lane];
        u32x4 g2 = emb8[(size_t)s2 * 6 + lane];
        u32x4 g3 = emb8[(size_t)s3 * 6 + lane];
        DEC16(A, g0); DEC16(A, g1); DEC16(A, g2); DEC16(A, g3);
    }
    for (; j < cnt; ++j) {
        u32x4 g0 = emb8[(size_t)sp[j] * 6 + lane];
        DEC16(A, g0);
    }

    f32x4 o0 = {A[0].x, A[0].y, A[1].x, A[1].y};
    f32x4 o1 = {A[2].x, A[2].y, A[3].x, A[3].y};
    f32x4 o2 = {A[4].x, A[4].y, A[5].x, A[5].y};
    f32x4 o3 = {A[6].x, A[6].y, A[7].x, A[7].y};

    f32x4* outrow = (f32x4*)(out + (size_t)node * OUT_DIM);
    const f32x4* w4 = (const f32x4*)w;
    float c = (float)cnt;
    int q = lane * 4;
    __builtin_nontemporal_store(o0, outrow + q);
    __builtin_nontemporal_store(o1, outrow + q + 1);
    __builtin_nontemporal_store(o2, outrow + q + 2);
    __builtin_nontemporal_store(o3, outrow + q + 3);
    f32x4 p0 = c * w4[q], p1 = c * w4[q + 1], p2 = c * w4[q + 2], p3 = c * w4[q + 3];
    __builtin_nontemporal_store(p0, outrow + 24 + q);
    __builtin_nontemporal_store(p1, outrow + 24 + q + 1);
    __builtin_nontemporal_store(p2, outrow + 24 + q + 2);
    __builtin_nontemporal_store(p3, outrow + 24 + q + 3);
}
#endif  // HAVE_FP8

// ---------------- bf16 aggregation (fallback tier) --------------------------

#define ACC8(A, g)                                                        \
    {                                                                     \
        A[0] += __uint_as_float((g).x << 16);                             \
        A[1] += __uint_as_float((g).x & 0xffff0000u);                     \
        A[2] += __uint_as_float((g).y << 16);                             \
        A[3] += __uint_as_float((g).y & 0xffff0000u);                     \
        A[4] += __uint_as_float((g).z << 16);                             \
        A[5] += __uint_as_float((g).z & 0xffff0000u);                     \
        A[6] += __uint_as_float((g).w << 16);                             \
        A[7] += __uint_as_float((g).w & 0xffff0000u);                     \
    }

__global__ __launch_bounds__(192) void aggb_k(
        const u32x4* __restrict__ embb,      // [N, 12] u32x4 (bf16)
        const float* __restrict__ w,
        const int* __restrict__ offs,
        const int* __restrict__ sorted_src,
        float* __restrict__ out, int n_nodes, int n_edges) {
    int t = threadIdx.x;
    int sub = t / 12;
    int lane = t - sub * 12;
    int node = blockIdx.x * 16 + sub;
    if (node >= n_nodes) return;

    int start = offs[node];
    int endp = (node + 1 < n_nodes) ? offs[node + 1] : n_edges;
    int cnt = endp - start;
    const int* sp = sorted_src + start;

    float aA[8] = {0.f, 0.f, 0.f, 0.f, 0.f, 0.f, 0.f, 0.f};
    float aB[8] = {0.f, 0.f, 0.f, 0.f, 0.f, 0.f, 0.f, 0.f};
    int j = 0;
    if (cnt >= 8) {
        int s0 = sp[0], s1 = sp[1], s2 = sp[2], s3 = sp[3];
        for (; j + 7 < cnt; j += 4) {
            int t0 = sp[j + 4], t1 = sp[j + 5], t2 = sp[j + 6], t3 = sp[j + 7];
            u32x4 g0 = embb[(size_t)s0 * 12 + lane];
            u32x4 g1 = embb[(size_t)s1 * 12 + lane];
            u32x4 g2 = embb[(size_t)s2 * 12 + lane];
            u32x4 g3 = embb[(size_t)s3 * 12 + lane];
            ACC8(aA, g0); ACC8(aB, g1); ACC8(aA, g2); ACC8(aB, g3);
            s0 = t0; s1 = t1; s2 = t2; s3 = t3;
        }
        u32x4 g0 = embb[(size_t)s0 * 12 + lane];
        u32x4 g1 = embb[(size_t)s1 * 12 + lane];
        u32x4 g2 = embb[(size_t)s2 * 12 + lane];
        u32x4 g3 = embb[(size_t)s3 * 12 + lane];
        ACC8(aA, g0); ACC8(aB, g1); ACC8(aA, g2); ACC8(aB, g3);
        j += 4;
    }
    for (; j + 3 < cnt; j += 4) {
        int s0 = sp[j], s1 = sp[j + 1], s2 = sp[j + 2], s3 = sp[j + 3];
        u32x4 g0 = embb[(size_t)s0 * 12 + lane];
        u32x4 g1 = embb[(size_t)s1 * 12 + lane];
        u32x4 g2 = embb[(size_t)s2 * 12 + lane];
        u32x4 g3 = embb[(size_t)s3 * 12 + lane];
        ACC8(aA, g0); ACC8(aB, g1); ACC8(aA, g2); ACC8(aB, g3);
    }
    for (; j < cnt; ++j) {
        u32x4 g0 = embb[(size_t)sp[j] * 12 + lane];
        ACC8(aA, g0);
    }

    f32x4 lo = {aA[0] + aB[0], aA[1] + aB[1], aA[2] + aB[2], aA[3] + aB[3]};
    f32x4 hi = {aA[4] + aB[4], aA[5] + aB[5], aA[6] + aB[6], aA[7] + aB[7]};

    f32x4* outrow = (f32x4*)(out + (size_t)node * OUT_DIM);
    const f32x4* w4 = (const f32x4*)w;
    float c = (float)cnt;
    f32x4 plo = c * w4[lane * 2];
    f32x4 phi = c * w4[lane * 2 + 1];
    __builtin_nontemporal_store(lo, outrow + lane * 2);
    __builtin_nontemporal_store(hi, outrow + lane * 2 + 1);
    __builtin_nontemporal_store(plo, outrow + 24 + lane * 2);
    __builtin_nontemporal_store(phi, outrow + 24 + lane * 2 + 1);
}

// ---------------- f32 mid-tier agg (kept as fallback) ----------------------
__global__ __launch_bounds__(NODES_PER_BLK * LPN) void agg4p_k(
        const f32x4* __restrict__ emb4,
        const f32x4* __restrict__ w4,
        const int* __restrict__ offs,
        const int* __restrict__ sorted_src,
        float* __restrict__ out, int n_nodes, int n_edges) {
    int t = threadIdx.x;
    int sub = t / LPN;
    int lane = t - sub * LPN;
    int node = blockIdx.x * NODES_PER_BLK + sub;
    if (node >= n_nodes) return;

    int start = offs[node];
    int endp = (node + 1 < n_nodes) ? offs[node + 1] : n_edges;
    int cnt = endp - start;
    const int* sp = sorted_src + start;

    f32x4 a0 = {0.f, 0.f, 0.f, 0.f};
    f32x4 a1 = a0, a2 = a0, a3 = a0;
    int j = 0;
    for (; j + 3 < cnt; j += 4) {
        int s0 = sp[j], s1 = sp[j + 1], s2 = sp[j + 2], s3 = sp[j + 3];
        f32x4 v0 = emb4[(size_t)s0 * LPN + lane];
        f32x4 v1 = emb4[(size_t)s1 * LPN + lane];
        f32x4 v2 = emb4[(size_t)s2 * LPN + lane];
        f32x4 v3 = emb4[(size_t)s3 * LPN + lane];
        a0 += v0; a1 += v1; a2 += v2; a3 += v3;
    }
    for (; j < cnt; ++j) {
        a0 += emb4[(size_t)sp[j] * LPN + lane];
    }
    f32x4 ft = (a0 + a1) + (a2 + a3);

    f32x4* outrow = (f32x4*)(out + (size_t)node * OUT_DIM);
    float c = (float)cnt;
    f32x4 pv = c * w4[lane];
    __builtin_nontemporal_store(ft, outrow + lane);
    __builtin_nontemporal_store(pv, outrow + LPN + lane);
}

extern "C" void kernel_launch(void* const* d_in, const int* in_sizes, int n_in,
                              void* d_out, int out_size, void* d_ws, size_t ws_size,
                              hipStream_t stream) {
    const float* emb = (const float*)d_in[0];   // [N, 96] f32
    const float* w   = (const float*)d_in[1];   // [1, 96] f32
    const int*   src = (const int*)d_in[2];     // [E] int32
    const int*   dst = (const int*)d_in[3];     // [E] int32
    float* out = (float*)d_out;                 // [N, 192] f32

    const int n_nodes = in_sizes[0] / D_FEAT;
    const int n_edges = in_sizes[2];
    const int nr = (n_nodes + RNG_NODES - 1) >> RNG_SHIFT;   // node ranges
    const int cnt_len = nr * NBLK_A;
    const int nb_cnt = (cnt_len + SCAN_BLK - 1) / SCAN_BLK;  // == nr
    const int chunk = (n_edges + NBLK_A - 1) / NBLK_A;

    // ws (int32): cnt[cnt_len] | aux[SCAN_BLK] | offs[N] | pack[E]
    //             | sorted_src[E] | (align16) embq[N*48 bf16 / N*24 fp8]
    size_t base_ints = (size_t)cnt_len + SCAN_BLK + n_nodes + 2 * (size_t)n_edges;
    size_t embq_off  = (base_ints + 3) & ~(size_t)3;          // 16B align
    size_t need_f32  = base_ints * sizeof(int);
    size_t need_bf16 = (embq_off + (size_t)n_nodes * 48) * sizeof(int);
    size_t need_fp8  = (embq_off + (size_t)n_nodes * 24) * sizeof(int);
    bool ok = (nr <= SCAN_BLK) && (nb_cnt <= SCAN_BLK) &&
              (n_nodes <= (1 << (31 - RNG_SHIFT - 1)));       // src<<8 fits in int31

    if (ws_size < need_f32 || !ok) {
        // fallback: round-1 atomic path (correct, slower)
        float* deg = (float*)d_ws;
        int n_out = n_nodes * OUT_DIM;
        int blocks = (n_out + 255) / 256;
        if (blocks > 2048) blocks = 2048;
        zero_k<<<blocks, 256, 0, stream>>>(out, deg, n_out, n_nodes);
        degf_k<<<(n_edges + 255) / 256, 256, 0, stream>>>(dst, deg, n_edges);
        long long total = (long long)n_edges * D_FEAT;
        scatter_k<<<(int)((total + 255) / 256), 256, 0, stream>>>(emb, src, dst, out, n_edges);
        prompt_k<<<(n_nodes * P_DIM + 255) / 256, 256, 0, stream>>>(w, deg, out, n_nodes);
        return;
    }

    int* cnt        = (int*)d_ws;
    int* aux        = cnt + cnt_len;
    int* offs       = aux + SCAN_BLK;
    int* pack       = offs + n_nodes;
    int* sorted_src = pack + n_edges;
    u32x4* embq     = (u32x4*)((int*)d_ws + embq_off);

    int mode = 0;                              // 0=f32, 1=bf16, 2=fp8
    int nq = 0;
#if HAVE_FP8
    if (ws_size >= need_fp8) { mode = 2; nq = n_nodes * 6; }
    else if (ws_size >= need_bf16) { mode = 1; nq = n_nodes * 12; }
#else
    if (ws_size >= need_bf16) { mode = 1; nq = n_nodes * 12; }
#endif

    conv_hist_k<<<NBLK_A, BIG_T, 0, stream>>>((const f32x4*)emb, embq, nq, mode,
                                              dst, cnt, n_edges, nr, chunk);
    scan_block_k<<<nb_cnt, SCAN_BLK, 0, stream>>>(cnt, aux, cnt_len);
    binwrite_k<<<NBLK_A, BIG_T, 0, stream>>>(src, dst, cnt, aux, pack, n_edges, nr, chunk);
    finesort_k<<<nr, BIG_T, 0, stream>>>(aux, pack, offs, sorted_src, n_nodes, n_edges, nr);
#if HAVE_FP8
    if (mode == 2) {
        aggf8_k<<<(n_nodes + 31) / 32, 192, 0, stream>>>(
            embq, w, offs, sorted_src, out, n_nodes, n_edges);
    } else
#endif
    if (mode == 1) {
        aggb_k<<<(n_nodes + 15) / 16, 192, 0, stream>>>(
            embq, w, offs, sorted_src, out, n_nodes, n_edges);
    } else {
        agg4p_k<<<(n_nodes + NODES_PER_BLK - 1) / NODES_PER_BLK, NODES_PER_BLK * LPN, 0, stream>>>(
            (const f32x4*)emb, (const f32x4*)w, offs, sorted_src, out, n_nodes, n_edges);
    }
}

// Round 13
// 53.041 us; speedup vs baseline: 1.3880x; 1.3880x over previous
//
#include <hip/hip_runtime.h>

#define D_FEAT 96
#define P_DIM 96
#define OUT_DIM 192
#define SCAN_BLK 256
#define NODES_PER_BLK 8
#define LPN 24          // f32 path: lanes per node (24 x float4)
#define RNG_SHIFT 8     // 256 nodes per range
#define RNG_NODES 256
#define NBLK_A 256      // binning blocks (== SCAN_BLK so scan chunks == ranges)
#define BIG_T 1024      // threads for binning kernels
#define FS_CAP 6144     // finesort LDS window capacity (ints, 24KB)

// gfx950 guaranteed: fp8 cvt builtins are device-only; do NOT gate on
// __has_builtin (false in the host pass -- R11 bug).
#define HAVE_FP8 1

typedef float f32x4 __attribute__((ext_vector_type(4)));
typedef float f32x2 __attribute__((ext_vector_type(2)));
typedef unsigned int u32;
typedef u32 u32x4 __attribute__((ext_vector_type(4)));
typedef u32 u32x2 __attribute__((ext_vector_type(2)));

// ---------------- fallback (round-1) kernels ------------------------------
__global__ __launch_bounds__(256) void zero_k(float* __restrict__ out,
                                              float* __restrict__ deg,
                                              int n_out, int n_deg) {
    int stride = gridDim.x * blockDim.x;
    for (int i = blockIdx.x * blockDim.x + threadIdx.x; i < n_out; i += stride)
        out[i] = 0.0f;
    for (int i = blockIdx.x * blockDim.x + threadIdx.x; i < n_deg; i += stride)
        deg[i] = 0.0f;
}

__global__ __launch_bounds__(256) void degf_k(const int* __restrict__ dst,
                                              float* __restrict__ deg,
                                              int n_edges) {
    int e = blockIdx.x * blockDim.x + threadIdx.x;
    if (e < n_edges) atomicAdd(deg + dst[e], 1.0f);
}

__global__ __launch_bounds__(256) void scatter_k(const float* __restrict__ emb,
                                                 const int* __restrict__ src,
                                                 const int* __restrict__ dst,
                                                 float* __restrict__ out,
                                                 int n_edges) {
    int idx = blockIdx.x * blockDim.x + threadIdx.x;
    int e = idx / D_FEAT;
    if (e >= n_edges) return;
    int c = idx - e * D_FEAT;
    atomicAdd(out + (size_t)dst[e] * OUT_DIM + c, emb[(size_t)src[e] * D_FEAT + c]);
}

__global__ __launch_bounds__(256) void prompt_k(const float* __restrict__ w,
                                                const float* __restrict__ deg,
                                                float* __restrict__ out,
                                                int n_nodes) {
    int idx = blockIdx.x * blockDim.x + threadIdx.x;
    if (idx >= n_nodes * P_DIM) return;
    int v = idx / P_DIM;
    int c = idx - v * P_DIM;
    out[(size_t)v * OUT_DIM + P_DIM + c] = deg[v] * w[c];
}

// ---------------- convert helpers -------------------------------------------

__device__ __forceinline__ u32 f2bf_rn(float f) {
    u32 b = __float_as_uint(f);
    return (b + 0x7fffu + ((b >> 16) & 1u)) >> 16;   // round-to-nearest-even
}

#if HAVE_FP8
__device__ __forceinline__ u32 enc4_fp8(float a, float b, float c, float d) {
    u32 r = __builtin_amdgcn_cvt_pk_fp8_f32(a, b, 0u, false);   // bytes 0,1
    r = __builtin_amdgcn_cvt_pk_fp8_f32(c, d, r, true);          // bytes 2,3
    return r;
}
#endif

// ---------------- deterministic two-pass binned counting sort --------------

// Fused: table convert (mode 0=none, 1=bf16, 2=fp8) + per-block range hist.
__global__ __launch_bounds__(BIG_T) void conv_hist_k(
        const f32x4* __restrict__ emb4, u32x4* __restrict__ embq,
        int nq, int mode,
        const int* __restrict__ dst, int* __restrict__ cnt,
        int n_edges, int nr, int chunk) {
    int b = blockIdx.x, t = threadIdx.x;
    int gs = gridDim.x * BIG_T;
    int gid = b * BIG_T + t;
    if (mode == 1) {                       // bf16: out u32x4 <- 8 f32 (2 f32x4)
        for (int i = gid; i < nq; i += gs) {
            f32x4 a = emb4[2 * i];
            f32x4 c = emb4[2 * i + 1];
            u32x4 o;
            o.x = f2bf_rn(a.x) | (f2bf_rn(a.y) << 16);
            o.y = f2bf_rn(a.z) | (f2bf_rn(a.w) << 16);
            o.z = f2bf_rn(c.x) | (f2bf_rn(c.y) << 16);
            o.w = f2bf_rn(c.z) | (f2bf_rn(c.w) << 16);
            embq[i] = o;
        }
    }
#if HAVE_FP8
    else if (mode == 2) {                  // fp8: out u32x4 <- 16 f32 (4 f32x4)
        for (int i = gid; i < nq; i += gs) {
            f32x4 a = emb4[4 * i];
            f32x4 b4 = emb4[4 * i + 1];
            f32x4 c = emb4[4 * i + 2];
            f32x4 d = emb4[4 * i + 3];
            u32x4 o;
            o.x = enc4_fp8(a.x, a.y, a.z, a.w);
            o.y = enc4_fp8(b4.x, b4.y, b4.z, b4.w);
            o.z = enc4_fp8(c.x, c.y, c.z, c.w);
            o.w = enc4_fp8(d.x, d.y, d.z, d.w);
            embq[i] = o;
        }
    }
#endif
    __shared__ int h[RNG_NODES];
    if (t < RNG_NODES) h[t] = 0;
    __syncthreads();
    int beg = b * chunk;
    int end = beg + chunk; if (end > n_edges) end = n_edges;
    for (int i = beg + t; i < end; i += BIG_T)
        atomicAdd(&h[dst[i] >> RNG_SHIFT], 1);
    __syncthreads();
    if (t < nr) cnt[t * NBLK_A + b] = h[t];
}

// Per-256-chunk exclusive scan in place; aux[r] = range total (chunk==range).
__global__ __launch_bounds__(SCAN_BLK) void scan_block_k(int* __restrict__ cnt,
                                                         int* __restrict__ aux, int n) {
    __shared__ int buf[SCAN_BLK];
    int t = threadIdx.x;
    int i = blockIdx.x * SCAN_BLK + t;
    int v = (i < n) ? cnt[i] : 0;
    buf[t] = v;
    __syncthreads();
    for (int off = 1; off < SCAN_BLK; off <<= 1) {
        int x = (t >= off) ? buf[t - off] : 0;
        __syncthreads();
        buf[t] += x;
        __syncthreads();
    }
    if (i < n) cnt[i] = buf[t] - v;
    if (t == SCAN_BLK - 1) aux[blockIdx.x] = buf[t];
}

// 256 blocks x 1024 threads: append packed (src<<8 | dst&255) into this
// block's private slice of each range region (16 edges/slice -> full lines).
__global__ __launch_bounds__(BIG_T) void binwrite_k(const int* __restrict__ src,
                                                    const int* __restrict__ dst,
                                                    const int* __restrict__ cnt,
                                                    const int* __restrict__ aux,
                                                    int* __restrict__ pack,
                                                    int n_edges, int nr, int chunk) {
    __shared__ int buf[SCAN_BLK];
    __shared__ int cur[RNG_NODES];
    int b = blockIdx.x, t = threadIdx.x;
    int av = 0;
    if (t < SCAN_BLK) { av = (t < nr) ? aux[t] : 0; buf[t] = av; }
    __syncthreads();
    for (int off = 1; off < SCAN_BLK; off <<= 1) {
        int x = 0;
        if (t < SCAN_BLK && t >= off) x = buf[t - off];
        __syncthreads();
        if (t < SCAN_BLK) buf[t] += x;
        __syncthreads();
    }
    if (t < nr) cur[t] = (buf[t] - av) + cnt[t * NBLK_A + b];
    __syncthreads();
    int beg = b * chunk;
    int end = beg + chunk; if (end > n_edges) end = n_edges;
    for (int i = beg + t; i < end; i += BIG_T) {
        int d = dst[i];
        int pos = atomicAdd(&cur[d >> RNG_SHIFT], 1);
        pack[pos] = (src[i] << RNG_SHIFT) | (d & (RNG_NODES - 1));
    }
}

// nr blocks x 1024 threads: stage window in LDS, hist + scan -> offs[], place.
__global__ __launch_bounds__(BIG_T) void finesort_k(const int* __restrict__ aux,
                                                    const int* __restrict__ pack,
                                                    int* __restrict__ offs,
                                                    int* __restrict__ sorted_src,
                                                    int n_nodes, int n_edges, int nr) {
    __shared__ int buf[SCAN_BLK];
    __shared__ int h[RNG_NODES];
    __shared__ int cur[RNG_NODES];
    __shared__ int win[FS_CAP];
    int r = blockIdx.x, t = threadIdx.x;
    int av = 0;
    if (t < SCAN_BLK) { av = (t < nr) ? aux[t] : 0; buf[t] = av; }
    __syncthreads();
    for (int off = 1; off < SCAN_BLK; off <<= 1) {
        int x = 0;
        if (t < SCAN_BLK && t >= off) x = buf[t - off];
        __syncthreads();
        if (t < SCAN_BLK) buf[t] += x;
        __syncthreads();
    }
    int start = buf[r] - aux[r];
    int end = buf[r];
    int wlen = end - start;
    bool fits = (wlen <= FS_CAP);
    if (t < RNG_NODES) h[t] = 0;
    __syncthreads();
    if (fits) {
        for (int i = t; i < wlen; i += BIG_T) {
            int p = pack[start + i];
            win[i] = p;
            atomicAdd(&h[p & (RNG_NODES - 1)], 1);
        }
    } else {
        for (int i = start + t; i < end; i += BIG_T)
            atomicAdd(&h[pack[i] & (RNG_NODES - 1)], 1);
    }
    __syncthreads();
    int v = (t < RNG_NODES) ? h[t] : 0;
    for (int off = 1; off < RNG_NODES; off <<= 1) {
        int x = 0;
        if (t < RNG_NODES && t >= off) x = h[t - off];
        __syncthreads();
        if (t < RNG_NODES) h[t] += x;
        __syncthreads();
    }
    if (t < RNG_NODES) {
        int o = start + h[t] - v;
        int node = (r << RNG_SHIFT) + t;
        if (node < n_nodes) offs[node] = o;
        cur[t] = o;
    }
    __syncthreads();
    if (fits) {
        for (int i = t; i < wlen; i += BIG_T) {
            int p = win[i];
            int pos = atomicAdd(&cur[p & (RNG_NODES - 1)], 1);
            sorted_src[pos] = p >> RNG_SHIFT;
        }
    } else {
        for (int i = start + t; i < end; i += BIG_T) {
            int p = pack[i];
            int pos = atomicAdd(&cur[p & (RNG_NODES - 1)], 1);
            sorted_src[pos] = p >> RNG_SHIFT;
        }
    }
}

// ---------------- fp8 aggregation -------------------------------------------

#if HAVE_FP8
// 12 lanes/node x u32x2 (8 fp8 feats each); gathers 96B contiguous/edge;
// A/B alternating accumulators; lane-contiguous 2x16B NT stores (aggb shape).
#define DEC8(A, g)                                                          \
    {                                                                       \
        A[0] += __builtin_amdgcn_cvt_pk_f32_fp8((g).x, false);              \
        A[1] += __builtin_amdgcn_cvt_pk_f32_fp8((g).x, true);               \
        A[2] += __builtin_amdgcn_cvt_pk_f32_fp8((g).y, false);              \
        A[3] += __builtin_amdgcn_cvt_pk_f32_fp8((g).y, true);               \
    }

__global__ __launch_bounds__(192) void aggf8_k(
        const u32x2* __restrict__ emb8,      // [N, 12] u32x2 (fp8)
        const float* __restrict__ w,         // [96] f32
        const int* __restrict__ offs,
        const int* __restrict__ sorted_src,
        float* __restrict__ out, int n_nodes, int n_edges) {
    int t = threadIdx.x;
    int sub = t / 12;
    int lane = t - sub * 12;                 // u32x2 column 0..11 (8 feats each)
    int node = blockIdx.x * 16 + sub;
    if (node >= n_nodes) return;

    int start = offs[node];
    int endp = (node + 1 < n_nodes) ? offs[node + 1] : n_edges;
    int cnt = endp - start;
    const int* sp = sorted_src + start;

    f32x2 A[4], B[4];
    #pragma unroll
    for (int k = 0; k < 4; ++k) { A[k] = (f32x2){0.f, 0.f}; B[k] = (f32x2){0.f, 0.f}; }

    int j = 0;
    if (cnt >= 8) {
        int s0 = sp[0], s1 = sp[1], s2 = sp[2], s3 = sp[3];
        for (; j + 7 < cnt; j += 4) {
            int t0 = sp[j + 4], t1 = sp[j + 5], t2 = sp[j + 6], t3 = sp[j + 7];
            u32x2 g0 = emb8[(size_t)s0 * 12 + lane];
            u32x2 g1 = emb8[(size_t)s1 * 12 + lane];
            u32x2 g2 = emb8[(size_t)s2 * 12 + lane];
            u32x2 g3 = emb8[(size_t)s3 * 12 + lane];
            DEC8(A, g0); DEC8(B, g1); DEC8(A, g2); DEC8(B, g3);
            s0 = t0; s1 = t1; s2 = t2; s3 = t3;
        }
        u32x2 g0 = emb8[(size_t)s0 * 12 + lane];
        u32x2 g1 = emb8[(size_t)s1 * 12 + lane];
        u32x2 g2 = emb8[(size_t)s2 * 12 + lane];
        u32x2 g3 = emb8[(size_t)s3 * 12 + lane];
        DEC8(A, g0); DEC8(B, g1); DEC8(A, g2); DEC8(B, g3);
        j += 4;
    }
    for (; j + 3 < cnt; j += 4) {
        int s0 = sp[j], s1 = sp[j + 1], s2 = sp[j + 2], s3 = sp[j + 3];
        u32x2 g0 = emb8[(size_t)s0 * 12 + lane];
        u32x2 g1 = emb8[(size_t)s1 * 12 + lane];
        u32x2 g2 = emb8[(size_t)s2 * 12 + lane];
        u32x2 g3 = emb8[(size_t)s3 * 12 + lane];
        DEC8(A, g0); DEC8(B, g1); DEC8(A, g2); DEC8(B, g3);
    }
    for (; j < cnt; ++j) {
        u32x2 g0 = emb8[(size_t)sp[j] * 12 + lane];
        DEC8(A, g0);
    }

    f32x4 lo = {A[0].x + B[0].x, A[0].y + B[0].y, A[1].x + B[1].x, A[1].y + B[1].y};
    f32x4 hi = {A[2].x + B[2].x, A[2].y + B[2].y, A[3].x + B[3].x, A[3].y + B[3].y};

    f32x4* outrow = (f32x4*)(out + (size_t)node * OUT_DIM);
    const f32x4* w4 = (const f32x4*)w;
    float c = (float)cnt;
    f32x4 plo = c * w4[lane * 2];
    f32x4 phi = c * w4[lane * 2 + 1];
    __builtin_nontemporal_store(lo, outrow + lane * 2);
    __builtin_nontemporal_store(hi, outrow + lane * 2 + 1);
    __builtin_nontemporal_store(plo, outrow + 24 + lane * 2);
    __builtin_nontemporal_store(phi, outrow + 24 + lane * 2 + 1);
}
#endif  // HAVE_FP8

// ---------------- bf16 aggregation (fallback tier) --------------------------

#define ACC8(A, g)                                                        \
    {                                                                     \
        A[0] += __uint_as_float((g).x << 16);                             \
        A[1] += __uint_as_float((g).x & 0xffff0000u);                     \
        A[2] += __uint_as_float((g).y << 16);                             \
        A[3] += __uint_as_float((g).y & 0xffff0000u);                     \
        A[4] += __uint_as_float((g).z << 16);                             \
        A[5] += __uint_as_float((g).z & 0xffff0000u);                     \
        A[6] += __uint_as_float((g).w << 16);                             \
        A[7] += __uint_as_float((g).w & 0xffff0000u);                     \
    }

__global__ __launch_bounds__(192) void aggb_k(
        const u32x4* __restrict__ embb,      // [N, 12] u32x4 (bf16)
        const float* __restrict__ w,
        const int* __restrict__ offs,
        const int* __restrict__ sorted_src,
        float* __restrict__ out, int n_nodes, int n_edges) {
    int t = threadIdx.x;
    int sub = t / 12;
    int lane = t - sub * 12;
    int node = blockIdx.x * 16 + sub;
    if (node >= n_nodes) return;

    int start = offs[node];
    int endp = (node + 1 < n_nodes) ? offs[node + 1] : n_edges;
    int cnt = endp - start;
    const int* sp = sorted_src + start;

    float aA[8] = {0.f, 0.f, 0.f, 0.f, 0.f, 0.f, 0.f, 0.f};
    float aB[8] = {0.f, 0.f, 0.f, 0.f, 0.f, 0.f, 0.f, 0.f};
    int j = 0;
    if (cnt >= 8) {
        int s0 = sp[0], s1 = sp[1], s2 = sp[2], s3 = sp[3];
        for (; j + 7 < cnt; j += 4) {
            int t0 = sp[j + 4], t1 = sp[j + 5], t2 = sp[j + 6], t3 = sp[j + 7];
            u32x4 g0 = embb[(size_t)s0 * 12 + lane];
            u32x4 g1 = embb[(size_t)s1 * 12 + lane];
            u32x4 g2 = embb[(size_t)s2 * 12 + lane];
            u32x4 g3 = embb[(size_t)s3 * 12 + lane];
            ACC8(aA, g0); ACC8(aB, g1); ACC8(aA, g2); ACC8(aB, g3);
            s0 = t0; s1 = t1; s2 = t2; s3 = t3;
        }
        u32x4 g0 = embb[(size_t)s0 * 12 + lane];
        u32x4 g1 = embb[(size_t)s1 * 12 + lane];
        u32x4 g2 = embb[(size_t)s2 * 12 + lane];
        u32x4 g3 = embb[(size_t)s3 * 12 + lane];
        ACC8(aA, g0); ACC8(aB, g1); ACC8(aA, g2); ACC8(aB, g3);
        j += 4;
    }
    for (; j + 3 < cnt; j += 4) {
        int s0 = sp[j], s1 = sp[j + 1], s2 = sp[j + 2], s3 = sp[j + 3];
        u32x4 g0 = embb[(size_t)s0 * 12 + lane];
        u32x4 g1 = embb[(size_t)s1 * 12 + lane];
        u32x4 g2 = embb[(size_t)s2 * 12 + lane];
        u32x4 g3 = embb[(size_t)s3 * 12 + lane];
        ACC8(aA, g0); ACC8(aB, g1); ACC8(aA, g2); ACC8(aB, g3);
    }
    for (; j < cnt; ++j) {
        u32x4 g0 = embb[(size_t)sp[j] * 12 + lane];
        ACC8(aA, g0);
    }

    f32x4 lo = {aA[0] + aB[0], aA[1] + aB[1], aA[2] + aB[2], aA[3] + aB[3]};
    f32x4 hi = {aA[4] + aB[4], aA[5] + aB[5], aA[6] + aB[6], aA[7] + aB[7]};

    f32x4* outrow = (f32x4*)(out + (size_t)node * OUT_DIM);
    const f32x4* w4 = (const f32x4*)w;
    float c = (float)cnt;
    f32x4 plo = c * w4[lane * 2];
    f32x4 phi = c * w4[lane * 2 + 1];
    __builtin_nontemporal_store(lo, outrow + lane * 2);
    __builtin_nontemporal_store(hi, outrow + lane * 2 + 1);
    __builtin_nontemporal_store(plo, outrow + 24 + lane * 2);
    __builtin_nontemporal_store(phi, outrow + 24 + lane * 2 + 1);
}

// ---------------- f32 mid-tier agg (kept as fallback) ----------------------
__global__ __launch_bounds__(NODES_PER_BLK * LPN) void agg4p_k(
        const f32x4* __restrict__ emb4,
        const f32x4* __restrict__ w4,
        const int* __restrict__ offs,
        const int* __restrict__ sorted_src,
        float* __restrict__ out, int n_nodes, int n_edges) {
    int t = threadIdx.x;
    int sub = t / LPN;
    int lane = t - sub * LPN;
    int node = blockIdx.x * NODES_PER_BLK + sub;
    if (node >= n_nodes) return;

    int start = offs[node];
    int endp = (node + 1 < n_nodes) ? offs[node + 1] : n_edges;
    int cnt = endp - start;
    const int* sp = sorted_src + start;

    f32x4 a0 = {0.f, 0.f, 0.f, 0.f};
    f32x4 a1 = a0, a2 = a0, a3 = a0;
    int j = 0;
    for (; j + 3 < cnt; j += 4) {
        int s0 = sp[j], s1 = sp[j + 1], s2 = sp[j + 2], s3 = sp[j + 3];
        f32x4 v0 = emb4[(size_t)s0 * LPN + lane];
        f32x4 v1 = emb4[(size_t)s1 * LPN + lane];
        f32x4 v2 = emb4[(size_t)s2 * LPN + lane];
        f32x4 v3 = emb4[(size_t)s3 * LPN + lane];
        a0 += v0; a1 += v1; a2 += v2; a3 += v3;
    }
    for (; j < cnt; ++j) {
        a0 += emb4[(size_t)sp[j] * LPN + lane];
    }
    f32x4 ft = (a0 + a1) + (a2 + a3);

    f32x4* outrow = (f32x4*)(out + (size_t)node * OUT_DIM);
    float c = (float)cnt;
    f32x4 pv = c * w4[lane];
    __builtin_nontemporal_store(ft, outrow + lane);
    __builtin_nontemporal_store(pv, outrow + LPN + lane);
}

extern "C" void kernel_launch(void* const* d_in, const int* in_sizes, int n_in,
                              void* d_out, int out_size, void* d_ws, size_t ws_size,
                              hipStream_t stream) {
    const float* emb = (const float*)d_in[0];   // [N, 96] f32
    const float* w   = (const float*)d_in[1];   // [1, 96] f32
    const int*   src = (const int*)d_in[2];     // [E] int32
    const int*   dst = (const int*)d_in[3];     // [E] int32
    float* out = (float*)d_out;                 // [N, 192] f32

    const int n_nodes = in_sizes[0] / D_FEAT;
    const int n_edges = in_sizes[2];
    const int nr = (n_nodes + RNG_NODES - 1) >> RNG_SHIFT;   // node ranges
    const int cnt_len = nr * NBLK_A;
    const int nb_cnt = (cnt_len + SCAN_BLK - 1) / SCAN_BLK;  // == nr
    const int chunk = (n_edges + NBLK_A - 1) / NBLK_A;

    // ws (int32): cnt[cnt_len] | aux[SCAN_BLK] | offs[N] | pack[E]
    //             | sorted_src[E] | (align16) embq[N*48 bf16 / N*24 fp8]
    size_t base_ints = (size_t)cnt_len + SCAN_BLK + n_nodes + 2 * (size_t)n_edges;
    size_t embq_off  = (base_ints + 3) & ~(size_t)3;          // 16B align
    size_t need_f32  = base_ints * sizeof(int);
    size_t need_bf16 = (embq_off + (size_t)n_nodes * 48) * sizeof(int);
    size_t need_fp8  = (embq_off + (size_t)n_nodes * 24) * sizeof(int);
    bool ok = (nr <= SCAN_BLK) && (nb_cnt <= SCAN_BLK) &&
              (n_nodes <= (1 << (31 - RNG_SHIFT - 1)));       // src<<8 fits in int31

    if (ws_size < need_f32 || !ok) {
        // fallback: round-1 atomic path (correct, slower)
        float* deg = (float*)d_ws;
        int n_out = n_nodes * OUT_DIM;
        int blocks = (n_out + 255) / 256;
        if (blocks > 2048) blocks = 2048;
        zero_k<<<blocks, 256, 0, stream>>>(out, deg, n_out, n_nodes);
        degf_k<<<(n_edges + 255) / 256, 256, 0, stream>>>(dst, deg, n_edges);
        long long total = (long long)n_edges * D_FEAT;
        scatter_k<<<(int)((total + 255) / 256), 256, 0, stream>>>(emb, src, dst, out, n_edges);
        prompt_k<<<(n_nodes * P_DIM + 255) / 256, 256, 0, stream>>>(w, deg, out, n_nodes);
        return;
    }

    int* cnt        = (int*)d_ws;
    int* aux        = cnt + cnt_len;
    int* offs       = aux + SCAN_BLK;
    int* pack       = offs + n_nodes;
    int* sorted_src = pack + n_edges;
    u32x4* embq     = (u32x4*)((int*)d_ws + embq_off);

    int mode = 0;                              // 0=f32, 1=bf16, 2=fp8
    int nq = 0;
#if HAVE_FP8
    if (ws_size >= need_fp8) { mode = 2; nq = n_nodes * 6; }
    else if (ws_size >= need_bf16) { mode = 1; nq = n_nodes * 12; }
#else
    if (ws_size >= need_bf16) { mode = 1; nq = n_nodes * 12; }
#endif

    conv_hist_k<<<NBLK_A, BIG_T, 0, stream>>>((const f32x4*)emb, embq, nq, mode,
                                              dst, cnt, n_edges, nr, chunk);
    scan_block_k<<<nb_cnt, SCAN_BLK, 0, stream>>>(cnt, aux, cnt_len);
    binwrite_k<<<NBLK_A, BIG_T, 0, stream>>>(src, dst, cnt, aux, pack, n_edges, nr, chunk);
    finesort_k<<<nr, BIG_T, 0, stream>>>(aux, pack, offs, sorted_src, n_nodes, n_edges, nr);
#if HAVE_FP8
    if (mode == 2) {
        aggf8_k<<<(n_nodes + 15) / 16, 192, 0, stream>>>(
            (const u32x2*)embq, w, offs, sorted_src, out, n_nodes, n_edges);
    } else
#endif
    if (mode == 1) {
        aggb_k<<<(n_nodes + 15) / 16, 192, 0, stream>>>(
            embq, w, offs, sorted_src, out, n_nodes, n_edges);
    } else {
        agg4p_k<<<(n_nodes + NODES_PER_BLK - 1) / NODES_PER_BLK, NODES_PER_BLK * LPN, 0, stream>>>(
            (const f32x4*)emb, (const f32x4*)w, offs, sorted_src, out, n_nodes, n_edges);
    }
}